// Round 4
// baseline (534.644 us; speedup 1.0000x reference)
//
#include <hip/hip_runtime.h>
#include <cstdint>

#define NN 50000
#define NE 800000
static constexpr int HD = 128;     // H*D for every layer
static constexpr int FIN = 128;    // input feature dim for every layer
static constexpr int EF_DIM = 16;  // edge feature dim
static constexpr int SCAN_B = 256;
static constexpr int NPARTS = (NN + SCAN_B - 1) / SCAN_B;  // 196

// ============================ CSR build (once) ============================

__global__ void k_hist(const int* __restrict__ dst, int* __restrict__ deg) {
    int e = blockIdx.x * blockDim.x + threadIdx.x;
    if (e < NE) atomicAdd(&deg[dst[e]], 1);
}

__global__ __launch_bounds__(SCAN_B) void k_part(const int* __restrict__ deg,
                                                 int* __restrict__ part) {
    __shared__ int s[SCAN_B];
    int t = threadIdx.x;
    int i = blockIdx.x * SCAN_B + t;
    s[t] = (i < NN) ? deg[i] : 0;
    __syncthreads();
    for (int off = SCAN_B / 2; off > 0; off >>= 1) {
        if (t < off) s[t] += s[t + off];
        __syncthreads();
    }
    if (t == 0) part[blockIdx.x] = s[0];
}

__global__ __launch_bounds__(SCAN_B) void k_scanpart(int* __restrict__ part) {
    __shared__ int s[SCAN_B];
    int t = threadIdx.x;
    int v = (t < NPARTS) ? part[t] : 0;
    s[t] = v;
    __syncthreads();
    for (int off = 1; off < SCAN_B; off <<= 1) {
        int u = (t >= off) ? s[t - off] : 0;
        __syncthreads();
        s[t] += u;
        __syncthreads();
    }
    if (t < NPARTS) part[t] = s[t] - v;  // exclusive
}

__global__ __launch_bounds__(SCAN_B) void k_rowptr(const int* __restrict__ deg,
                                                   const int* __restrict__ part,
                                                   int* __restrict__ row_ptr,
                                                   int* __restrict__ cursor) {
    __shared__ int s[SCAN_B];
    int t = threadIdx.x;
    int i = blockIdx.x * SCAN_B + t;
    int v = (i < NN) ? deg[i] : 0;
    s[t] = v;
    __syncthreads();
    for (int off = 1; off < SCAN_B; off <<= 1) {
        int u = (t >= off) ? s[t - off] : 0;
        __syncthreads();
        s[t] += u;
        __syncthreads();
    }
    int excl = s[t] - v + part[blockIdx.x];
    if (i < NN) { row_ptr[i] = excl; cursor[i] = excl; }
    if (i == NN) row_ptr[NN] = NE;
}

// one packed 8B store per edge: epr[pos] = {orig_edge, src}
__global__ void k_scatter(const int* __restrict__ src, const int* __restrict__ dst,
                          int* __restrict__ cursor, int2* __restrict__ epr) {
    int e = blockIdx.x * blockDim.x + threadIdx.x;
    if (e >= NE) return;
    int d = dst[e];
    int pos = atomicAdd(&cursor[d], 1);
    epr[pos] = make_int2(e, src[e]);
}

// M[l*64 + f*H + h] = sum_d We_l[f, h*D+d] * ae_l[h,d]  for all three layers
__global__ void k_M3(const float* __restrict__ We0, const float* __restrict__ ae0,
                     const float* __restrict__ We1, const float* __restrict__ ae1,
                     const float* __restrict__ We2, const float* __restrict__ ae2,
                     float* __restrict__ M) {
    int l = blockIdx.x;
    int t = threadIdx.x;
    const float* We = (l == 0) ? We0 : (l == 1) ? We1 : We2;
    const float* ae = (l == 0) ? ae0 : (l == 1) ? ae1 : ae2;
    int H = (l == 2) ? 1 : 4;
    int D = (l == 2) ? 128 : 32;
    if (t >= EF_DIM * H) return;
    int f = t / H, h = t % H;
    float s = 0.f;
    for (int d = 0; d < D; d++) s += We[f * HD + h * D + d] * ae[h * D + d];
    M[l * 64 + f * H + h] = s;
}

// edge-feature projections for ALL layers, coalesced, original edge order
__global__ __launch_bounds__(256) void k_eproj(const float* __restrict__ EFt,
                                               const float* __restrict__ M,
                                               float* __restrict__ ep0,
                                               float* __restrict__ ep1,
                                               float* __restrict__ ep2) {
    __shared__ float sM[192];
    int t = threadIdx.x;
    if (t < 192) sM[t] = M[t];
    __syncthreads();
    int e = blockIdx.x * 256 + t;
    if (e >= NE) return;
    float ef[EF_DIM];
    const float4* efp = (const float4*)(EFt + (size_t)e * EF_DIM);
#pragma unroll
    for (int q = 0; q < 4; q++) {
        float4 v = efp[q];
        ef[4 * q] = v.x; ef[4 * q + 1] = v.y; ef[4 * q + 2] = v.z; ef[4 * q + 3] = v.w;
    }
    float o0[4] = {0.f, 0.f, 0.f, 0.f};
    float o1[4] = {0.f, 0.f, 0.f, 0.f};
    float o2 = 0.f;
#pragma unroll
    for (int f = 0; f < EF_DIM; f++) {
        float v = ef[f];
#pragma unroll
        for (int h = 0; h < 4; h++) {
            o0[h] += v * sM[f * 4 + h];
            o1[h] += v * sM[64 + f * 4 + h];
        }
        o2 += v * sM[128 + f];
    }
    ((float4*)ep0)[e] = make_float4(o0[0], o0[1], o0[2], o0[3]);
    ((float4*)ep1)[e] = make_float4(o1[0], o1[1], o1[2], o1[3]);
    ep2[e] = o2;
}

// ============================ per-layer kernels ============================

// feat = X @ W, 32-row tile, float4 LDS broadcast reads
__global__ __launch_bounds__(256) void k_feat(const float* __restrict__ X,
                                              const float* __restrict__ W,
                                              float* __restrict__ F) {
    __shared__ float4 sX[32][32];  // 32 rows x 128 floats
    const int t = threadIdx.x;
    const int col = t & 127;
    const int rg = (t >> 7) * 16;
    const int nbase = blockIdx.x * 32;
    const float4* Xv = (const float4*)X;
    for (int i = t; i < 1024; i += 256) {
        int r = i >> 5, q = i & 31;
        int n = nbase + r;
        sX[r][q] = (n < NN) ? Xv[(size_t)n * 32 + q] : make_float4(0.f, 0.f, 0.f, 0.f);
    }
    __syncthreads();
    float acc[16];
#pragma unroll
    for (int i = 0; i < 16; i++) acc[i] = 0.f;
    for (int q = 0; q < 32; q++) {
        float w0 = W[(4 * q + 0) * HD + col];
        float w1 = W[(4 * q + 1) * HD + col];
        float w2 = W[(4 * q + 2) * HD + col];
        float w3 = W[(4 * q + 3) * HD + col];
#pragma unroll
        for (int i = 0; i < 16; i++) {
            float4 xv = sX[rg + i][q];
            acc[i] += xv.x * w0 + xv.y * w1 + xv.z * w2 + xv.w * w3;
        }
    }
#pragma unroll
    for (int i = 0; i < 16; i++) {
        int n = nbase + rg + i;
        if (n < NN) F[(size_t)n * HD + col] = acc[i];
    }
}

// el[n,h] = <feat[n,h,:], al[h,:]> ; er likewise (float4)
__global__ void k_elr(const float* __restrict__ F, const float* __restrict__ al,
                      const float* __restrict__ ar, float* __restrict__ el,
                      float* __restrict__ er, int H, int D) {
    int idx = blockIdx.x * blockDim.x + threadIdx.x;  // n*H + h
    if (idx >= NN * H) return;
    int n = idx / H, h = idx % H;
    const float4* fr = (const float4*)(F + (size_t)n * HD + h * D);
    const float4* alr = (const float4*)(al + h * D);
    const float4* arr = (const float4*)(ar + h * D);
    float sl = 0.f, sr = 0.f;
    for (int q = 0; q < D / 4; q++) {
        float4 v = fr[q], A = alr[q], B = arr[q];
        sl += v.x * A.x + v.y * A.y + v.z * A.z + v.w * A.w;
        sr += v.x * B.x + v.y * B.y + v.z * B.z + v.w * B.w;
    }
    el[idx] = sl;
    er[idx] = sr;
}

// fused per-dst-node: score + softmax + aggregation. One WAVE per node.
__global__ __launch_bounds__(256) void k_node(const int* __restrict__ row_ptr,
                                              const int2* __restrict__ epr,
                                              const float* __restrict__ ep,
                                              const float* __restrict__ el,
                                              const float* __restrict__ er,
                                              float* __restrict__ esc,
                                              const float* __restrict__ F,
                                              const float* __restrict__ b,
                                              float* __restrict__ R,
                                              int H, int D, int act) {
    const int wave = threadIdx.x >> 6;
    const int lane = threadIdx.x & 63;
    const int n = blockIdx.x * 4 + wave;
    if (n >= NN) return;
    const int start = row_ptr[n];
    const int end = row_ptr[n + 1];
    const int c0 = lane, c1 = lane + 64;
    const int h0 = c0 / D, h1 = c1 / D;
    const float b0 = b[c0], b1 = b[c1];

    if (start == end) {
        float v0 = b0, v1 = b1;
        if (act) { v0 = fmaxf(v0, 0.f); v1 = fmaxf(v1, 0.f); }
        R[(size_t)n * HD + c0] = v0;
        R[(size_t)n * HD + c1] = v1;
        return;
    }

    const int hsh = (H == 4) ? 2 : 0;  // log2 H
    const int hm = H - 1;
    const int hh = lane & hm;          // this lane's score-head (j & hm is invariant)
    const float er_j = er[n * H + hh];

    // pass 1: raw scores -> esc, track per-head max
    float pmax = -3.0e38f;
    for (int j = start * H + lane; j < end * H; j += 64) {
        int i = j >> hsh;
        int2 es = epr[i];
        float x = el[es.y * H + hh] + er_j + ep[(size_t)es.x * H + hh];
        x = (x > 0.f) ? x : 0.2f * x;
        esc[j] = x;
        pmax = fmaxf(pmax, x);
    }
    for (int m = H; m < 64; m <<= 1) pmax = fmaxf(pmax, __shfl_xor(pmax, m));

    // pass 2: exp + sum, write exp back
    float psum = 0.f;
    for (int j = start * H + lane; j < end * H; j += 64) {
        float ex = __expf(esc[j] - pmax);
        esc[j] = ex;
        psum += ex;
    }
    for (int m = H; m < 64; m <<= 1) psum += __shfl_xor(psum, m);
    const float inv0 = 1.f / __shfl(psum, h0);
    const float inv1 = 1.f / __shfl(psum, h1);

    // pass 3: aggregate
    float a0 = 0.f, a1 = 0.f;
#pragma unroll 4
    for (int i = start; i < end; i++) {
        int sn = epr[i].y;
        const float* Fr = F + (size_t)sn * HD;
        float w0 = esc[(size_t)i * H + h0];
        float w1 = esc[(size_t)i * H + h1];
        a0 += Fr[c0] * w0;
        a1 += Fr[c1] * w1;
    }
    float v0 = a0 * inv0 + b0;
    float v1 = a1 * inv1 + b1;
    if (act) { v0 = fmaxf(v0, 0.f); v1 = fmaxf(v1, 0.f); }
    R[(size_t)n * HD + c0] = v0;
    R[(size_t)n * HD + c1] = v1;
}

// ============================ driver ============================

static void run_layer(const float* X, const int2* epr, const int* row_ptr,
                      const float* W, const float* al, const float* ar,
                      const float* b, const float* ep, int H, int D, int act,
                      float* featbuf, float* esc, float* el, float* er,
                      float* out, hipStream_t stream) {
    const int NH = NN * H;
    hipLaunchKernelGGL(k_feat, dim3((NN + 31) / 32), dim3(256), 0, stream, X, W, featbuf);
    hipLaunchKernelGGL(k_elr, dim3((NH + 255) / 256), dim3(256), 0, stream,
                       featbuf, al, ar, el, er, H, D);
    hipLaunchKernelGGL(k_node, dim3((NN + 3) / 4), dim3(256), 0, stream,
                       row_ptr, epr, ep, el, er, esc, featbuf, b, out, H, D, act);
}

extern "C" void kernel_launch(void* const* d_in, const int* in_sizes, int n_in,
                              void* d_out, int out_size, void* d_ws, size_t ws_size,
                              hipStream_t stream) {
    const float* h   = (const float*)d_in[0];
    const float* eft = (const float*)d_in[1];
    const int* src   = (const int*)d_in[2];
    const int* dst   = (const int*)d_in[3];
    auto P = [&](int i) { return (const float*)d_in[i]; };

    float* ws = (float*)d_ws;
    float* featbuf = ws;                            // 6.4M floats
    float* esc     = featbuf + (size_t)NN * HD;     // 3.2M
    float* ep0     = esc + (size_t)NE * 4;          // 3.2M
    float* ep1     = ep0 + (size_t)NE * 4;          // 3.2M
    float* ep2     = ep1 + (size_t)NE * 4;          // 0.8M
    float* el      = ep2 + (size_t)NE;              // 0.2M
    float* er      = el + (size_t)NN * 4;           // 0.2M
    float* M       = er + (size_t)NN * 4;           // 192
    int2* epr      = (int2*)(M + 192);              // NE int2 (8B-aligned)
    int* row_ptr   = (int*)(epr + NE);              // NN+1
    int* cursor    = row_ptr + (NN + 1);            // NN
    int* deg       = cursor + NN;                   // NN
    int* part      = deg + NN;                      // NPARTS
    float* out     = (float*)d_out;                 // also inter-layer activation buffer

    // ---- build CSR by dst + edge projections (once) ----
    hipMemsetAsync(deg, 0, NN * sizeof(int), stream);
    hipLaunchKernelGGL(k_hist, dim3((NE + 255) / 256), dim3(256), 0, stream, dst, deg);
    hipLaunchKernelGGL(k_part, dim3(NPARTS), dim3(SCAN_B), 0, stream, deg, part);
    hipLaunchKernelGGL(k_scanpart, dim3(1), dim3(SCAN_B), 0, stream, part);
    hipLaunchKernelGGL(k_rowptr, dim3(NPARTS), dim3(SCAN_B), 0, stream,
                       deg, part, row_ptr, cursor);
    hipLaunchKernelGGL(k_scatter, dim3((NE + 255) / 256), dim3(256), 0, stream,
                       src, dst, cursor, epr);
    hipLaunchKernelGGL(k_M3, dim3(3), dim3(64), 0, stream,
                       P(5), P(8), P(11), P(14), P(17), P(20), M);
    hipLaunchKernelGGL(k_eproj, dim3((NE + 255) / 256), dim3(256), 0, stream,
                       eft, M, ep0, ep1, ep2);

    // layer 0: h -> out (H=4, D=32, relu)   [out doubles as activation ping buffer]
    run_layer(h, epr, row_ptr, P(4), P(6), P(7), P(9), ep0,
              4, 32, 1, featbuf, esc, el, er, out, stream);
    // layer 1: out -> out (in-place: k_feat consumes X before k_node rewrites it)
    run_layer(out, epr, row_ptr, P(10), P(12), P(13), P(15), ep1,
              4, 32, 1, featbuf, esc, el, er, out, stream);
    // layer 2: out -> out (H=1, D=128, no act)
    run_layer(out, epr, row_ptr, P(16), P(18), P(19), P(21), ep2,
              1, 128, 0, featbuf, esc, el, er, out, stream);
}

// Round 5
// 477.364 us; speedup vs baseline: 1.1200x; 1.1200x over previous
//
#include <hip/hip_runtime.h>
#include <hip/hip_fp16.h>
#include <cstdint>

#define NN 50000
#define NE 800000
static constexpr int HD = 128;     // H*D for every layer
static constexpr int FIN = 128;    // input feature dim for every layer
static constexpr int EF_DIM = 16;  // edge feature dim
static constexpr int SCAN_B = 256;
static constexpr int NPARTS = (NN + SCAN_B - 1) / SCAN_B;  // 196

// ============================ CSR build (once) ============================

__global__ void k_hist(const int* __restrict__ dst, int* __restrict__ deg) {
    int e = blockIdx.x * blockDim.x + threadIdx.x;
    if (e < NE) atomicAdd(&deg[dst[e]], 1);
}

__global__ __launch_bounds__(SCAN_B) void k_part(const int* __restrict__ deg,
                                                 int* __restrict__ part) {
    __shared__ int s[SCAN_B];
    int t = threadIdx.x;
    int i = blockIdx.x * SCAN_B + t;
    s[t] = (i < NN) ? deg[i] : 0;
    __syncthreads();
    for (int off = SCAN_B / 2; off > 0; off >>= 1) {
        if (t < off) s[t] += s[t + off];
        __syncthreads();
    }
    if (t == 0) part[blockIdx.x] = s[0];
}

__global__ __launch_bounds__(SCAN_B) void k_scanpart(int* __restrict__ part) {
    __shared__ int s[SCAN_B];
    int t = threadIdx.x;
    int v = (t < NPARTS) ? part[t] : 0;
    s[t] = v;
    __syncthreads();
    for (int off = 1; off < SCAN_B; off <<= 1) {
        int u = (t >= off) ? s[t - off] : 0;
        __syncthreads();
        s[t] += u;
        __syncthreads();
    }
    if (t < NPARTS) part[t] = s[t] - v;  // exclusive
}

__global__ __launch_bounds__(SCAN_B) void k_rowptr(const int* __restrict__ deg,
                                                   const int* __restrict__ part,
                                                   int* __restrict__ row_ptr,
                                                   int* __restrict__ cursor) {
    __shared__ int s[SCAN_B];
    int t = threadIdx.x;
    int i = blockIdx.x * SCAN_B + t;
    int v = (i < NN) ? deg[i] : 0;
    s[t] = v;
    __syncthreads();
    for (int off = 1; off < SCAN_B; off <<= 1) {
        int u = (t >= off) ? s[t - off] : 0;
        __syncthreads();
        s[t] += u;
        __syncthreads();
    }
    int excl = s[t] - v + part[blockIdx.x];
    if (i < NN) { row_ptr[i] = excl; cursor[i] = excl; }
    if (i == NN) row_ptr[NN] = NE;
}

// arrival-order scatter (order fixed up by k_segsort): epr[pos] = {orig_edge, src}
__global__ void k_scatter(const int* __restrict__ src, const int* __restrict__ dst,
                          int* __restrict__ cursor, int2* __restrict__ epr) {
    int e = blockIdx.x * blockDim.x + threadIdx.x;
    if (e >= NE) return;
    int d = dst[e];
    int pos = atomicAdd(&cursor[d], 1);
    epr[pos] = make_int2(e, src[e]);
}

// per-segment rank sort by (src, orig_edge): deterministic + src-locality sweep.
// one wave per node; segments <=128 (deg is Poisson(16), >128 never happens,
// but the >128 path is still correct, just unsorted).
__global__ __launch_bounds__(256) void k_segsort(const int* __restrict__ row_ptr,
                                                 const int2* __restrict__ epr,
                                                 int* __restrict__ ssrc,
                                                 int* __restrict__ eidx) {
    __shared__ int2 seg[4][128];
    const int wave = threadIdx.x >> 6;
    const int lane = threadIdx.x & 63;
    const int n = blockIdx.x * 4 + wave;  // grid exactly NN/4: n always < NN
    const int start = row_ptr[n];
    const int len = row_ptr[n + 1] - start;
    const bool small = (len > 0 && len <= 128);
    if (small)
        for (int s = lane; s < len; s += 64) seg[wave][s] = epr[start + s];
    __syncthreads();
    if (small) {
        for (int s = lane; s < len; s += 64) {
            int2 me = seg[wave][s];
            int rank = 0;
            for (int j = 0; j < len; j++) {
                int2 o = seg[wave][j];
                rank += (o.y < me.y) || (o.y == me.y && o.x < me.x);
            }
            ssrc[start + rank] = me.y;
            eidx[start + rank] = me.x;
        }
    } else if (len > 128) {
        for (int s = lane; s < len; s += 64) {
            int2 v = epr[start + s];
            ssrc[start + s] = v.y;
            eidx[start + s] = v.x;
        }
    }
}

// M[l*64 + f*H + h] = sum_d We_l[f, h*D+d] * ae_l[h,d]  for all three layers
__global__ void k_M3(const float* __restrict__ We0, const float* __restrict__ ae0,
                     const float* __restrict__ We1, const float* __restrict__ ae1,
                     const float* __restrict__ We2, const float* __restrict__ ae2,
                     float* __restrict__ M) {
    int l = blockIdx.x;
    int t = threadIdx.x;
    const float* We = (l == 0) ? We0 : (l == 1) ? We1 : We2;
    const float* ae = (l == 0) ? ae0 : (l == 1) ? ae1 : ae2;
    int H = (l == 2) ? 1 : 4;
    int D = (l == 2) ? 128 : 32;
    if (t >= EF_DIM * H) return;
    int f = t / H, h = t % H;
    float s = 0.f;
    for (int d = 0; d < D; d++) s += We[f * HD + h * D + d] * ae[h * D + d];
    M[l * 64 + f * H + h] = s;
}

// edge projections for all layers, IN SORTED EDGE ORDER (EF row = 64B = 1 line,
// so the gather costs the same fetch as a coalesced read; outputs sequential).
__global__ __launch_bounds__(256) void k_eproj(const float* __restrict__ EFt,
                                               const int* __restrict__ eidx,
                                               const float* __restrict__ M,
                                               float4* __restrict__ ep0,
                                               float4* __restrict__ ep1,
                                               float* __restrict__ ep2) {
    __shared__ float sM[192];
    int t = threadIdx.x;
    if (t < 192) sM[t] = M[t];
    __syncthreads();
    int i = blockIdx.x * 256 + t;
    if (i >= NE) return;
    int e = eidx[i];
    float ef[EF_DIM];
    const float4* efp = (const float4*)(EFt + (size_t)e * EF_DIM);
#pragma unroll
    for (int q = 0; q < 4; q++) {
        float4 v = efp[q];
        ef[4 * q] = v.x; ef[4 * q + 1] = v.y; ef[4 * q + 2] = v.z; ef[4 * q + 3] = v.w;
    }
    float o0[4] = {0.f, 0.f, 0.f, 0.f};
    float o1[4] = {0.f, 0.f, 0.f, 0.f};
    float o2 = 0.f;
#pragma unroll
    for (int f = 0; f < EF_DIM; f++) {
        float v = ef[f];
#pragma unroll
        for (int h = 0; h < 4; h++) {
            o0[h] += v * sM[f * 4 + h];
            o1[h] += v * sM[64 + f * 4 + h];
        }
        o2 += v * sM[128 + f];
    }
    ep0[i] = make_float4(o0[0], o0[1], o0[2], o0[3]);
    ep1[i] = make_float4(o1[0], o1[1], o1[2], o1[3]);
    ep2[i] = o2;
}

// ============================ per-layer kernels ============================

// feat = X @ W -> fp16 F. 32-row tile; wave w owns 8 rows; thread owns col-pair.
__global__ __launch_bounds__(256) void k_feat(const float* __restrict__ X,
                                              const float* __restrict__ W,
                                              __half2* __restrict__ Fh) {
    __shared__ float4 sX[32][32];  // 32 rows x 128 floats
    const int t = threadIdx.x;
    const int cp = t & 63;          // col pair: cols {2cp, 2cp+1}
    const int rg = (t >> 6) * 8;    // row group of 8
    const int nbase = blockIdx.x * 32;
    const float4* Xv = (const float4*)X;
    for (int i = t; i < 1024; i += 256) {
        int r = i >> 5, q = i & 31;
        int n = nbase + r;
        sX[r][q] = (n < NN) ? Xv[(size_t)n * 32 + q] : make_float4(0.f, 0.f, 0.f, 0.f);
    }
    __syncthreads();
    float2 acc[8];
#pragma unroll
    for (int i = 0; i < 8; i++) acc[i] = make_float2(0.f, 0.f);
    for (int q = 0; q < 32; q++) {
        float2 w0 = ((const float2*)(W + (4 * q + 0) * HD))[cp];
        float2 w1 = ((const float2*)(W + (4 * q + 1) * HD))[cp];
        float2 w2 = ((const float2*)(W + (4 * q + 2) * HD))[cp];
        float2 w3 = ((const float2*)(W + (4 * q + 3) * HD))[cp];
#pragma unroll
        for (int i = 0; i < 8; i++) {
            float4 x = sX[rg + i][q];
            acc[i].x += x.x * w0.x + x.y * w1.x + x.z * w2.x + x.w * w3.x;
            acc[i].y += x.x * w0.y + x.y * w1.y + x.z * w2.y + x.w * w3.y;
        }
    }
#pragma unroll
    for (int i = 0; i < 8; i++) {
        int n = nbase + rg + i;
        if (n < NN) Fh[(size_t)n * 64 + cp] = __floats2half2_rn(acc[i].x, acc[i].y);
    }
}

// el[n,h] = <feat[n,h,:], al[h,:]> ; er likewise (fp16 feat)
__global__ void k_elr(const __half2* __restrict__ Fh, const float* __restrict__ al,
                      const float* __restrict__ ar, float* __restrict__ el,
                      float* __restrict__ er, int H, int D) {
    int idx = blockIdx.x * blockDim.x + threadIdx.x;  // n*H + h
    if (idx >= NN * H) return;
    int n = idx / H, h = idx % H;
    const __half2* fr = Fh + (size_t)n * 64 + h * (D / 2);
    const float2* alr = (const float2*)(al + h * D);
    const float2* arr = (const float2*)(ar + h * D);
    float sl = 0.f, sr = 0.f;
    for (int q = 0; q < D / 2; q++) {
        float2 v = __half22float2(fr[q]);
        float2 A = alr[q], B = arr[q];
        sl += v.x * A.x + v.y * A.y;
        sr += v.x * B.x + v.y * B.y;
    }
    el[idx] = sl;
    er[idx] = sr;
}

// fused per-dst-node: score + softmax + aggregation. One WAVE per node.
// ssrc/ep/esc sequential; random traffic = el gather (L2-resident) + fp16 F rows.
__global__ __launch_bounds__(256) void k_node(const int* __restrict__ row_ptr,
                                              const int* __restrict__ ssrc,
                                              const float* __restrict__ ep,
                                              const float* __restrict__ el,
                                              const float* __restrict__ er,
                                              float* __restrict__ esc,
                                              const __half2* __restrict__ Fh,
                                              const float* __restrict__ b,
                                              float* __restrict__ R,
                                              int H, int D, int act) {
    const int wave = threadIdx.x >> 6;
    const int lane = threadIdx.x & 63;
    const int n = blockIdx.x * 4 + wave;  // grid exactly NN/4
    const int start = row_ptr[n];
    const int end = row_ptr[n + 1];
    const int c = 2 * lane;               // this thread's col pair
    const int hcol = c / D;
    const float2 b2 = make_float2(b[c], b[c + 1]);

    if (start == end) {
        float2 v = b2;
        if (act) { v.x = fmaxf(v.x, 0.f); v.y = fmaxf(v.y, 0.f); }
        ((float2*)R)[(size_t)n * 64 + lane] = v;
        return;
    }

    const int hsh = (H == 4) ? 2 : 0;
    const int hm = H - 1;
    const int hh = lane & hm;          // score-slot head for this lane
    const float er_j = er[n * H + hh];

    // pass 1: raw scores -> esc (sequential), per-head max
    float pmax = -3.0e38f;
    for (int j = start * H + lane; j < end * H; j += 64) {
        int i = j >> hsh;
        int s = ssrc[i];
        float x = el[s * H + hh] + er_j + ep[j];
        x = (x > 0.f) ? x : 0.2f * x;
        esc[j] = x;
        pmax = fmaxf(pmax, x);
    }
    for (int m = H; m < 64; m <<= 1) pmax = fmaxf(pmax, __shfl_xor(pmax, m));

    // pass 2: exp + sum, write exp back
    float psum = 0.f;
    for (int j = start * H + lane; j < end * H; j += 64) {
        float ex = __expf(esc[j] - pmax);
        esc[j] = ex;
        psum += ex;
    }
    for (int m = H; m < 64; m <<= 1) psum += __shfl_xor(psum, m);
    const float inv = 1.f / __shfl(psum, hcol);

    // pass 3: aggregate fp16 rows
    float2 a = make_float2(0.f, 0.f);
#pragma unroll 4
    for (int i = start; i < end; i++) {
        int sn = ssrc[i];
        float w = esc[(size_t)i * H + hcol];
        float2 f2 = __half22float2(Fh[(size_t)sn * 64 + lane]);
        a.x += f2.x * w;
        a.y += f2.y * w;
    }
    float2 v = make_float2(a.x * inv + b2.x, a.y * inv + b2.y);
    if (act) { v.x = fmaxf(v.x, 0.f); v.y = fmaxf(v.y, 0.f); }
    ((float2*)R)[(size_t)n * 64 + lane] = v;
}

// ============================ driver ============================

static void run_layer(const float* X, const int* ssrc, const int* row_ptr,
                      const float* W, const float* al, const float* ar,
                      const float* b, const float* ep, int H, int D, int act,
                      __half2* Fh, float* esc, float* el, float* er,
                      float* out, hipStream_t stream) {
    const int NH = NN * H;
    hipLaunchKernelGGL(k_feat, dim3((NN + 31) / 32), dim3(256), 0, stream, X, W, Fh);
    hipLaunchKernelGGL(k_elr, dim3((NH + 255) / 256), dim3(256), 0, stream,
                       Fh, al, ar, el, er, H, D);
    hipLaunchKernelGGL(k_node, dim3(NN / 4), dim3(256), 0, stream,
                       row_ptr, ssrc, ep, el, er, esc, Fh, b, out, H, D, act);
}

extern "C" void kernel_launch(void* const* d_in, const int* in_sizes, int n_in,
                              void* d_out, int out_size, void* d_ws, size_t ws_size,
                              hipStream_t stream) {
    const float* h   = (const float*)d_in[0];
    const float* eft = (const float*)d_in[1];
    const int* src   = (const int*)d_in[2];
    const int* dst   = (const int*)d_in[3];
    auto P = [&](int i) { return (const float*)d_in[i]; };

    float* ws = (float*)d_ws;
    __half2* Fh    = (__half2*)ws;                  // NN*64 half2 = 3.2M floats
    float* esc     = ws + (size_t)NN * 64;          // 3.2M
    float* ep0     = esc + (size_t)NE * 4;          // 3.2M
    float* ep1     = ep0 + (size_t)NE * 4;          // 3.2M
    float* ep2     = ep1 + (size_t)NE * 4;          // 0.8M
    float* el      = ep2 + (size_t)NE;              // 0.2M
    float* er      = el + (size_t)NN * 4;           // 0.2M
    float* M       = er + (size_t)NN * 4;           // 192
    int2* epr      = (int2*)(M + 192);              // NE int2
    int* ssrc      = (int*)(epr + NE);              // NE
    int* eidx      = ssrc + NE;                     // NE
    int* row_ptr   = eidx + NE;                     // NN+1
    int* cursor    = row_ptr + (NN + 1);            // NN
    int* deg       = cursor + NN;                   // NN
    int* part      = deg + NN;                      // NPARTS
    float* out     = (float*)d_out;                 // also inter-layer activation buffer

    // ---- build sorted CSR by (dst, src) + edge projections (once) ----
    hipMemsetAsync(deg, 0, NN * sizeof(int), stream);
    hipLaunchKernelGGL(k_hist, dim3((NE + 255) / 256), dim3(256), 0, stream, dst, deg);
    hipLaunchKernelGGL(k_part, dim3(NPARTS), dim3(SCAN_B), 0, stream, deg, part);
    hipLaunchKernelGGL(k_scanpart, dim3(1), dim3(SCAN_B), 0, stream, part);
    hipLaunchKernelGGL(k_rowptr, dim3(NPARTS), dim3(SCAN_B), 0, stream,
                       deg, part, row_ptr, cursor);
    hipLaunchKernelGGL(k_scatter, dim3((NE + 255) / 256), dim3(256), 0, stream,
                       src, dst, cursor, epr);
    hipLaunchKernelGGL(k_segsort, dim3(NN / 4), dim3(256), 0, stream,
                       row_ptr, epr, ssrc, eidx);
    hipLaunchKernelGGL(k_M3, dim3(3), dim3(64), 0, stream,
                       P(5), P(8), P(11), P(14), P(17), P(20), M);
    hipLaunchKernelGGL(k_eproj, dim3((NE + 255) / 256), dim3(256), 0, stream,
                       eft, eidx, M, (float4*)ep0, (float4*)ep1, ep2);

    // layer 0: h -> out (H=4, D=32, relu)   [out doubles as activation ping buffer]
    run_layer(h, ssrc, row_ptr, P(4), P(6), P(7), P(9), ep0,
              4, 32, 1, Fh, esc, el, er, out, stream);
    // layer 1: out -> out (in-place: k_feat consumes X before k_node rewrites it)
    run_layer(out, ssrc, row_ptr, P(10), P(12), P(13), P(15), ep1,
              4, 32, 1, Fh, esc, el, er, out, stream);
    // layer 2: out -> out (H=1, D=128, no act)
    run_layer(out, ssrc, row_ptr, P(16), P(18), P(19), P(21), ep2,
              1, 128, 0, Fh, esc, el, er, out, stream);
}

// Round 6
// 411.784 us; speedup vs baseline: 1.2984x; 1.1593x over previous
//
#include <hip/hip_runtime.h>
#include <hip/hip_fp16.h>
#include <cstdint>

#define NN 50000
#define NE 800000
static constexpr int HD = 128;     // H*D for every layer
static constexpr int EF_DIM = 16;  // edge feature dim
static constexpr int SCAN_B = 256;
static constexpr int NPARTS = (NN + SCAN_B - 1) / SCAN_B;  // 196

typedef _Float16 f16x4 __attribute__((ext_vector_type(4)));
typedef float f32x4 __attribute__((ext_vector_type(4)));

// ============================ CSR build (once) ============================

__global__ void k_hist(const int* __restrict__ dst, int* __restrict__ deg) {
    int e = blockIdx.x * blockDim.x + threadIdx.x;
    if (e < NE) atomicAdd(&deg[dst[e]], 1);
}

__global__ __launch_bounds__(SCAN_B) void k_part(const int* __restrict__ deg,
                                                 int* __restrict__ part) {
    __shared__ int s[SCAN_B];
    int t = threadIdx.x;
    int i = blockIdx.x * SCAN_B + t;
    s[t] = (i < NN) ? deg[i] : 0;
    __syncthreads();
    for (int off = SCAN_B / 2; off > 0; off >>= 1) {
        if (t < off) s[t] += s[t + off];
        __syncthreads();
    }
    if (t == 0) part[blockIdx.x] = s[0];
}

__global__ __launch_bounds__(SCAN_B) void k_scanpart(int* __restrict__ part) {
    __shared__ int s[SCAN_B];
    int t = threadIdx.x;
    int v = (t < NPARTS) ? part[t] : 0;
    s[t] = v;
    __syncthreads();
    for (int off = 1; off < SCAN_B; off <<= 1) {
        int u = (t >= off) ? s[t - off] : 0;
        __syncthreads();
        s[t] += u;
        __syncthreads();
    }
    if (t < NPARTS) part[t] = s[t] - v;  // exclusive
}

__global__ __launch_bounds__(SCAN_B) void k_rowptr(const int* __restrict__ deg,
                                                   const int* __restrict__ part,
                                                   int* __restrict__ row_ptr,
                                                   int* __restrict__ cursor) {
    __shared__ int s[SCAN_B];
    int t = threadIdx.x;
    int i = blockIdx.x * SCAN_B + t;
    int v = (i < NN) ? deg[i] : 0;
    s[t] = v;
    __syncthreads();
    for (int off = 1; off < SCAN_B; off <<= 1) {
        int u = (t >= off) ? s[t - off] : 0;
        __syncthreads();
        s[t] += u;
        __syncthreads();
    }
    int excl = s[t] - v + part[blockIdx.x];
    if (i < NN) { row_ptr[i] = excl; cursor[i] = excl; }
    if (i == NN) row_ptr[NN] = NE;
}

__global__ void k_scatter(const int* __restrict__ src, const int* __restrict__ dst,
                          int* __restrict__ cursor, int2* __restrict__ epr) {
    int e = blockIdx.x * blockDim.x + threadIdx.x;
    if (e >= NE) return;
    int d = dst[e];
    int pos = atomicAdd(&cursor[d], 1);
    epr[pos] = make_int2(e, src[e]);
}

// per-segment rank sort by (src, orig_edge): deterministic + src-locality sweep.
__global__ __launch_bounds__(256) void k_segsort(const int* __restrict__ row_ptr,
                                                 const int2* __restrict__ epr,
                                                 int* __restrict__ ssrc,
                                                 int* __restrict__ eidx) {
    __shared__ int2 seg[4][128];
    const int wave = threadIdx.x >> 6;
    const int lane = threadIdx.x & 63;
    const int n = blockIdx.x * 4 + wave;  // grid exactly NN/4
    const int start = row_ptr[n];
    const int len = row_ptr[n + 1] - start;
    const bool small = (len > 0 && len <= 128);
    if (small)
        for (int s = lane; s < len; s += 64) seg[wave][s] = epr[start + s];
    __syncthreads();
    if (small) {
        for (int s = lane; s < len; s += 64) {
            int2 me = seg[wave][s];
            int rank = 0;
            for (int j = 0; j < len; j++) {
                int2 o = seg[wave][j];
                rank += (o.y < me.y) || (o.y == me.y && o.x < me.x);
            }
            ssrc[start + rank] = me.y;
            eidx[start + rank] = me.x;
        }
    } else if (len > 128) {
        for (int s = lane; s < len; s += 64) {
            int2 v = epr[start + s];
            ssrc[start + s] = v.y;
            eidx[start + s] = v.x;
        }
    }
}

// M[l*64 + f*H + h] = sum_d We_l[f, h*D+d] * ae_l[h,d]  for all three layers
__global__ void k_M3(const float* __restrict__ We0, const float* __restrict__ ae0,
                     const float* __restrict__ We1, const float* __restrict__ ae1,
                     const float* __restrict__ We2, const float* __restrict__ ae2,
                     float* __restrict__ M) {
    int l = blockIdx.x;
    int t = threadIdx.x;
    const float* We = (l == 0) ? We0 : (l == 1) ? We1 : We2;
    const float* ae = (l == 0) ? ae0 : (l == 1) ? ae1 : ae2;
    int H = (l == 2) ? 1 : 4;
    int D = (l == 2) ? 128 : 32;
    if (t >= EF_DIM * H) return;
    int f = t / H, h = t % H;
    float s = 0.f;
    for (int d = 0; d < D; d++) s += We[f * HD + h * D + d] * ae[h * D + d];
    M[l * 64 + f * H + h] = s;
}

// edge projections for all layers, in sorted edge order
__global__ __launch_bounds__(256) void k_eproj(const float* __restrict__ EFt,
                                               const int* __restrict__ eidx,
                                               const float* __restrict__ M,
                                               float4* __restrict__ ep0,
                                               float4* __restrict__ ep1,
                                               float* __restrict__ ep2) {
    __shared__ float sM[192];
    int t = threadIdx.x;
    if (t < 192) sM[t] = M[t];
    __syncthreads();
    int i = blockIdx.x * 256 + t;
    if (i >= NE) return;
    int e = eidx[i];
    float ef[EF_DIM];
    const float4* efp = (const float4*)(EFt + (size_t)e * EF_DIM);
#pragma unroll
    for (int q = 0; q < 4; q++) {
        float4 v = efp[q];
        ef[4 * q] = v.x; ef[4 * q + 1] = v.y; ef[4 * q + 2] = v.z; ef[4 * q + 3] = v.w;
    }
    float o0[4] = {0.f, 0.f, 0.f, 0.f};
    float o1[4] = {0.f, 0.f, 0.f, 0.f};
    float o2 = 0.f;
#pragma unroll
    for (int f = 0; f < EF_DIM; f++) {
        float v = ef[f];
#pragma unroll
        for (int h = 0; h < 4; h++) {
            o0[h] += v * sM[f * 4 + h];
            o1[h] += v * sM[64 + f * 4 + h];
        }
        o2 += v * sM[128 + f];
    }
    ep0[i] = make_float4(o0[0], o0[1], o0[2], o0[3]);
    ep1[i] = make_float4(o1[0], o1[1], o1[2], o1[3]);
    ep2[i] = o2;
}

// fp32 -> fp16 vector convert (n4 = count/4)
__global__ void k_cvt(const float* __restrict__ in, _Float16* __restrict__ out, int n4) {
    int i = blockIdx.x * blockDim.x + threadIdx.x;
    if (i >= n4) return;
    float4 v = ((const float4*)in)[i];
    f16x4 o = {(_Float16)v.x, (_Float16)v.y, (_Float16)v.z, (_Float16)v.w};
    ((f16x4*)out)[i] = o;
}

// ============================ per-layer kernels ============================

// feat = Xh @ W -> fp16 Fh via MFMA 16x16x16 f16.
// Block: 4 waves = 64 rows; wave = 16 rows x 128 cols (8 n-tiles, 8 k-blocks).
// A: row=lane&15, k=(lane>>4)*4+j ; B: col=lane&15, same k ;
// D: col=lane&15, row=(lane>>4)*4+r  (learn_hip m89-verified family).
__global__ __launch_bounds__(256) void k_feat(const _Float16* __restrict__ Xh,
                                              const float* __restrict__ W,
                                              _Float16* __restrict__ Fh) {
    __shared__ _Float16 Wt[128][136];  // transposed W (fp16), +8 pad -> 2-way banks
    const int t = threadIdx.x;
    const int lane = t & 63;
    const int wv = t >> 6;
    for (int i = t; i < 128 * 128; i += 256) {  // stage W^T (convert fp32->fp16)
        int k = i >> 7, nn = i & 127;
        Wt[nn][k] = (_Float16)W[i];
    }
    const int nbase = blockIdx.x * 64;
    const int row = nbase + wv * 16 + (lane & 15);
    const int rclamp = (row < NN) ? row : NN - 1;
    const int ksub = (lane >> 4) * 4;
    f16x4 a[8];
#pragma unroll
    for (int kb = 0; kb < 8; kb++)
        a[kb] = *(const f16x4*)(Xh + (size_t)rclamp * 128 + kb * 16 + ksub);
    __syncthreads();
#pragma unroll
    for (int nt = 0; nt < 8; nt++) {
        f32x4 acc = {0.f, 0.f, 0.f, 0.f};
        const int nc = nt * 16 + (lane & 15);
#pragma unroll
        for (int kb = 0; kb < 8; kb++) {
            f16x4 bf = *(const f16x4*)(&Wt[nc][kb * 16 + ksub]);
            acc = __builtin_amdgcn_mfma_f32_16x16x16f16(a[kb], bf, acc, 0, 0, 0);
        }
        const int r0 = nbase + wv * 16 + (lane >> 4) * 4;
#pragma unroll
        for (int r = 0; r < 4; r++) {
            int ro = r0 + r;
            if (ro < NN) Fh[(size_t)ro * 128 + nt * 16 + (lane & 15)] = (_Float16)acc[r];
        }
    }
}

// el[n,h] = <feat[n,h,:], al[h,:]> ; er likewise (fp16 feat)
__global__ void k_elr(const __half2* __restrict__ Fh, const float* __restrict__ al,
                      const float* __restrict__ ar, float* __restrict__ el,
                      float* __restrict__ er, int H, int D) {
    int idx = blockIdx.x * blockDim.x + threadIdx.x;  // n*H + h
    if (idx >= NN * H) return;
    int n = idx / H, h = idx % H;
    const __half2* fr = Fh + (size_t)n * 64 + h * (D / 2);
    const float2* alr = (const float2*)(al + h * D);
    const float2* arr = (const float2*)(ar + h * D);
    float sl = 0.f, sr = 0.f;
    for (int q = 0; q < D / 2; q++) {
        float2 v = __half22float2(fr[q]);
        float2 A = alr[q], B = arr[q];
        sl += v.x * A.x + v.y * A.y;
        sr += v.x * B.x + v.y * B.y;
    }
    el[idx] = sl;
    er[idx] = sr;
}

// fused per-dst-node: score + softmax + aggregation. One WAVE per node.
// Scores live in per-wave LDS (256 slots); recompute fallback for huge segments.
__global__ __launch_bounds__(256) void k_node(const int* __restrict__ row_ptr,
                                              const int* __restrict__ ssrc,
                                              const float* __restrict__ ep,
                                              const float* __restrict__ el,
                                              const float* __restrict__ er,
                                              const __half2* __restrict__ Fh,
                                              const float* __restrict__ bias,
                                              float* __restrict__ Rf,
                                              _Float16* __restrict__ Rh,
                                              int H, int D, int act, int out16) {
    __shared__ float wlds[4][256];
    const int wave = threadIdx.x >> 6;
    const int lane = threadIdx.x & 63;
    const int n = blockIdx.x * 4 + wave;  // grid exactly NN/4
    const int start = row_ptr[n];
    const int end = row_ptr[n + 1];
    const int len = end - start;
    const int slots = len * H;
    const int c = 2 * lane;
    const int hcol = c / D;
    float2 b2 = make_float2(bias[c], bias[c + 1]);
    float2 a = make_float2(0.f, 0.f);

    if (len > 0) {
        const int hsh = (H == 4) ? 2 : 0;
        const int hh = lane & (H - 1);
        const float er_j = er[n * H + hh];
        const float* epb = ep + (size_t)start * H;
        float pmax = -3.0e38f, psum = 0.f;

        if (slots <= 256) {
            float* wp = wlds[wave];
            for (int jj = lane; jj < slots; jj += 64) {
                int i = start + (jj >> hsh);
                float x = el[ssrc[i] * H + hh] + er_j + epb[jj];
                x = (x > 0.f) ? x : 0.2f * x;
                wp[jj] = x;
                pmax = fmaxf(pmax, x);
            }
            for (int m = H; m < 64; m <<= 1) pmax = fmaxf(pmax, __shfl_xor(pmax, m));
            for (int jj = lane; jj < slots; jj += 64) {
                float ex = __expf(wp[jj] - pmax);
                wp[jj] = ex;
                psum += ex;
            }
            for (int m = H; m < 64; m <<= 1) psum += __shfl_xor(psum, m);
            const float inv = 1.f / __shfl(psum, hcol);
#pragma unroll 4
            for (int i = start; i < end; i++) {
                float w = wp[(i - start) * H + hcol];
                float2 f2 = __half22float2(Fh[(size_t)ssrc[i] * 64 + lane]);
                a.x += f2.x * w;
                a.y += f2.y * w;
            }
            a.x *= inv;
            a.y *= inv;
        } else {  // recompute fallback (never hit for Poisson(16) degrees; kept for correctness)
            for (int jj = lane; jj < slots; jj += 64) {
                int i = start + (jj >> hsh);
                float x = el[ssrc[i] * H + hh] + er_j + epb[jj];
                x = (x > 0.f) ? x : 0.2f * x;
                pmax = fmaxf(pmax, x);
            }
            for (int m = H; m < 64; m <<= 1) pmax = fmaxf(pmax, __shfl_xor(pmax, m));
            for (int jj = lane; jj < slots; jj += 64) {
                int i = start + (jj >> hsh);
                float x = el[ssrc[i] * H + hh] + er_j + epb[jj];
                x = (x > 0.f) ? x : 0.2f * x;
                psum += __expf(x - pmax);
            }
            for (int m = H; m < 64; m <<= 1) psum += __shfl_xor(psum, m);
            const float inv = 1.f / __shfl(psum, hcol);
            const float pm_c = __shfl(pmax, hcol);
            const float er_c = er[n * H + hcol];
            for (int i = start; i < end; i++) {
                int sn = ssrc[i];
                float x = el[sn * H + hcol] + er_c + epb[(i - start) * H + hcol];
                x = (x > 0.f) ? x : 0.2f * x;
                float w = __expf(x - pm_c);
                float2 f2 = __half22float2(Fh[(size_t)sn * 64 + lane]);
                a.x += f2.x * w;
                a.y += f2.y * w;
            }
            a.x *= inv;
            a.y *= inv;
        }
    }

    float2 v = make_float2(a.x + b2.x, a.y + b2.y);
    if (act) { v.x = fmaxf(v.x, 0.f); v.y = fmaxf(v.y, 0.f); }
    if (out16)
        ((__half2*)Rh)[(size_t)n * 64 + lane] = __floats2half2_rn(v.x, v.y);
    else
        ((float2*)Rf)[(size_t)n * 64 + lane] = v;
}

// ============================ driver ============================

static void run_layer(const _Float16* Xh, const int* ssrc, const int* row_ptr,
                      const float* W, const float* al, const float* ar,
                      const float* b, const float* ep, int H, int D, int act,
                      _Float16* Fh, float* el, float* er,
                      float* Rf, _Float16* Rh, int out16, hipStream_t stream) {
    const int NH = NN * H;
    hipLaunchKernelGGL(k_feat, dim3((NN + 63) / 64), dim3(256), 0, stream, Xh, W, Fh);
    hipLaunchKernelGGL(k_elr, dim3((NH + 255) / 256), dim3(256), 0, stream,
                       (const __half2*)Fh, al, ar, el, er, H, D);
    hipLaunchKernelGGL(k_node, dim3(NN / 4), dim3(256), 0, stream,
                       row_ptr, ssrc, ep, el, er, (const __half2*)Fh, b,
                       Rf, Rh, H, D, act, out16);
}

extern "C" void kernel_launch(void* const* d_in, const int* in_sizes, int n_in,
                              void* d_out, int out_size, void* d_ws, size_t ws_size,
                              hipStream_t stream) {
    const float* h   = (const float*)d_in[0];
    const float* eft = (const float*)d_in[1];
    const int* src   = (const int*)d_in[2];
    const int* dst   = (const int*)d_in[3];
    auto P = [&](int i) { return (const float*)d_in[i]; };

    float* ws = (float*)d_ws;
    _Float16* Fh   = (_Float16*)ws;                 // NN*128 halves = 3.2M floats
    _Float16* Xh   = (_Float16*)(ws + (size_t)3200000);  // NN*128 halves = 3.2M floats
    float* ep0     = ws + (size_t)6400000;          // 3.2M
    float* ep1     = ep0 + (size_t)NE * 4;          // 3.2M
    float* ep2     = ep1 + (size_t)NE * 4;          // 0.8M
    float* el      = ep2 + (size_t)NE;              // 0.2M
    float* er      = el + (size_t)NN * 4;           // 0.2M
    float* M       = er + (size_t)NN * 4;           // 192
    int2* epr      = (int2*)(M + 192);              // NE int2
    int* ssrc      = (int*)(epr + NE);              // NE
    int* eidx      = ssrc + NE;                     // NE
    int* row_ptr   = eidx + NE;                     // NN+1
    int* cursor    = row_ptr + (NN + 1);            // NN
    int* deg       = cursor + NN;                   // NN
    int* part      = deg + NN;                      // NPARTS
    float* out     = (float*)d_out;

    // ---- build sorted CSR by (dst, src) + edge projections + input cvt (once) ----
    hipMemsetAsync(deg, 0, NN * sizeof(int), stream);
    hipLaunchKernelGGL(k_hist, dim3((NE + 255) / 256), dim3(256), 0, stream, dst, deg);
    hipLaunchKernelGGL(k_part, dim3(NPARTS), dim3(SCAN_B), 0, stream, deg, part);
    hipLaunchKernelGGL(k_scanpart, dim3(1), dim3(SCAN_B), 0, stream, part);
    hipLaunchKernelGGL(k_rowptr, dim3(NPARTS), dim3(SCAN_B), 0, stream,
                       deg, part, row_ptr, cursor);
    hipLaunchKernelGGL(k_scatter, dim3((NE + 255) / 256), dim3(256), 0, stream,
                       src, dst, cursor, epr);
    hipLaunchKernelGGL(k_segsort, dim3(NN / 4), dim3(256), 0, stream,
                       row_ptr, epr, ssrc, eidx);
    hipLaunchKernelGGL(k_M3, dim3(3), dim3(64), 0, stream,
                       P(5), P(8), P(11), P(14), P(17), P(20), M);
    hipLaunchKernelGGL(k_eproj, dim3((NE + 255) / 256), dim3(256), 0, stream,
                       eft, eidx, M, (float4*)ep0, (float4*)ep1, ep2);
    hipLaunchKernelGGL(k_cvt, dim3((NN * 128 / 4 + 255) / 256), dim3(256), 0, stream,
                       h, Xh, NN * 128 / 4);

    // layer 0: Xh -> Xh (fp16, relu)
    run_layer(Xh, ssrc, row_ptr, P(4), P(6), P(7), P(9), ep0,
              4, 32, 1, Fh, el, er, nullptr, Xh, 1, stream);
    // layer 1: Xh -> Xh (fp16, relu)
    run_layer(Xh, ssrc, row_ptr, P(10), P(12), P(13), P(15), ep1,
              4, 32, 1, Fh, el, er, nullptr, Xh, 1, stream);
    // layer 2: Xh -> out (fp32, no act)
    run_layer(Xh, ssrc, row_ptr, P(16), P(18), P(19), P(21), ep2,
              1, 128, 0, Fh, el, er, out, nullptr, 0, stream);
}

// Round 7
// 411.122 us; speedup vs baseline: 1.3004x; 1.0016x over previous
//
#include <hip/hip_runtime.h>
#include <hip/hip_fp16.h>
#include <cstdint>

#define NN 50000
#define NE 800000
static constexpr int HD = 128;     // H*D for every layer
static constexpr int EF_DIM = 16;  // edge feature dim
static constexpr int SCAN_B = 256;
static constexpr int NPARTS = (NN + SCAN_B - 1) / SCAN_B;  // 196

typedef _Float16 f16x4 __attribute__((ext_vector_type(4)));
typedef float f32x4 __attribute__((ext_vector_type(4)));

// ============================ prep (merged, once) ============================
// blocks [0,196): zero deg | [196,199): M3 | [199,391): Wht transpose+cvt |
// [391,6641): Xh fp32->fp16
__global__ __launch_bounds__(256) void k_prep(const float* __restrict__ h,
        const float* __restrict__ We0, const float* __restrict__ ae0,
        const float* __restrict__ We1, const float* __restrict__ ae1,
        const float* __restrict__ We2, const float* __restrict__ ae2,
        const float* __restrict__ W0, const float* __restrict__ W1,
        const float* __restrict__ W2,
        int* __restrict__ deg, float* __restrict__ M,
        _Float16* __restrict__ Wht, _Float16* __restrict__ Xh) {
    const int b = blockIdx.x, t = threadIdx.x;
    if (b < 196) {
        int i = b * 256 + t;
        if (i < NN) deg[i] = 0;
        return;
    }
    if (b < 199) {
        int l = b - 196;
        const float* We = (l == 0) ? We0 : (l == 1) ? We1 : We2;
        const float* ae = (l == 0) ? ae0 : (l == 1) ? ae1 : ae2;
        int H = (l == 2) ? 1 : 4, D = (l == 2) ? 128 : 32;
        if (t < EF_DIM * H) {
            int f = t / H, hh = t % H;
            float s = 0.f;
            for (int d = 0; d < D; d++) s += We[f * HD + hh * D + d] * ae[hh * D + d];
            M[l * 64 + f * H + hh] = s;
        }
        return;
    }
    if (b < 391) {
        int i = (b - 199) * 256 + t;     // over 3*128*128
        int l = i >> 14, rem = i & 16383;
        int n = rem >> 7, k = rem & 127;
        const float* W = (l == 0) ? W0 : (l == 1) ? W1 : W2;
        Wht[(size_t)l * 16384 + n * 128 + k] = (_Float16)W[k * 128 + n];
        return;
    }
    {
        int i = (b - 391) * 256 + t;     // over NN*32 float4's
        if (i < NN * 32) {
            float4 v = ((const float4*)h)[i];
            f16x4 o = {(_Float16)v.x, (_Float16)v.y, (_Float16)v.z, (_Float16)v.w};
            ((f16x4*)Xh)[i] = o;
        }
    }
}

// ============================ CSR build (once) ============================

__global__ void k_hist(const int* __restrict__ dst, int* __restrict__ deg) {
    int e = blockIdx.x * blockDim.x + threadIdx.x;
    if (e < NE) atomicAdd(&deg[dst[e]], 1);
}

__global__ __launch_bounds__(SCAN_B) void k_part(const int* __restrict__ deg,
                                                 int* __restrict__ part) {
    __shared__ int s[SCAN_B];
    int t = threadIdx.x;
    int i = blockIdx.x * SCAN_B + t;
    s[t] = (i < NN) ? deg[i] : 0;
    __syncthreads();
    for (int off = SCAN_B / 2; off > 0; off >>= 1) {
        if (t < off) s[t] += s[t + off];
        __syncthreads();
    }
    if (t == 0) part[blockIdx.x] = s[0];
}

__global__ __launch_bounds__(SCAN_B) void k_scanpart(int* __restrict__ part) {
    __shared__ int s[SCAN_B];
    int t = threadIdx.x;
    int v = (t < NPARTS) ? part[t] : 0;
    s[t] = v;
    __syncthreads();
    for (int off = 1; off < SCAN_B; off <<= 1) {
        int u = (t >= off) ? s[t - off] : 0;
        __syncthreads();
        s[t] += u;
        __syncthreads();
    }
    if (t < NPARTS) part[t] = s[t] - v;  // exclusive
}

__global__ __launch_bounds__(SCAN_B) void k_rowptr(const int* __restrict__ deg,
                                                   const int* __restrict__ part,
                                                   int* __restrict__ row_ptr,
                                                   int* __restrict__ cursor) {
    __shared__ int s[SCAN_B];
    int t = threadIdx.x;
    int i = blockIdx.x * SCAN_B + t;
    int v = (i < NN) ? deg[i] : 0;
    s[t] = v;
    __syncthreads();
    for (int off = 1; off < SCAN_B; off <<= 1) {
        int u = (t >= off) ? s[t - off] : 0;
        __syncthreads();
        s[t] += u;
        __syncthreads();
    }
    int excl = s[t] - v + part[blockIdx.x];
    if (i < NN) { row_ptr[i] = excl; cursor[i] = excl; }
    if (i == NN) row_ptr[NN] = NE;
}

__global__ void k_scatter(const int* __restrict__ src, const int* __restrict__ dst,
                          int* __restrict__ cursor, int2* __restrict__ epr) {
    int e = blockIdx.x * blockDim.x + threadIdx.x;
    if (e >= NE) return;
    int d = dst[e];
    int pos = atomicAdd(&cursor[d], 1);
    epr[pos] = make_int2(e, src[e]);
}

// in-place per-segment rank sort of epr by (src, orig_edge): deterministic order.
__global__ __launch_bounds__(256) void k_segsort(const int* __restrict__ row_ptr,
                                                 int2* __restrict__ epr) {
    __shared__ int2 seg[4][128];
    const int wave = threadIdx.x >> 6;
    const int lane = threadIdx.x & 63;
    const int n = blockIdx.x * 4 + wave;  // grid exactly NN/4
    const int start = row_ptr[n];
    const int len = row_ptr[n + 1] - start;
    const bool small = (len > 0 && len <= 128);
    if (small)
        for (int s = lane; s < len; s += 64) seg[wave][s] = epr[start + s];
    __syncthreads();
    if (small) {
        for (int s = lane; s < len; s += 64) {
            int2 me = seg[wave][s];
            int rank = 0;
            for (int j = 0; j < len; j++) {
                int2 o = seg[wave][j];
                rank += (o.y < me.y) || (o.y == me.y && o.x < me.x);
            }
            epr[start + rank] = me;
        }
    }
    // len > 128: leave arrival order (never happens for Poisson(16); still correct)
}

// edge projections for all layers, sorted edge order, fp16 outputs
__global__ __launch_bounds__(256) void k_eproj(const float* __restrict__ EFt,
                                               const int2* __restrict__ epr,
                                               const float* __restrict__ M,
                                               _Float16* __restrict__ ep0,
                                               _Float16* __restrict__ ep1,
                                               _Float16* __restrict__ ep2) {
    __shared__ float sM[192];
    int t = threadIdx.x;
    if (t < 192) sM[t] = M[t];
    __syncthreads();
    int i = blockIdx.x * 256 + t;
    if (i >= NE) return;
    int e = epr[i].x;
    float ef[EF_DIM];
    const float4* efp = (const float4*)(EFt + (size_t)e * EF_DIM);
#pragma unroll
    for (int q = 0; q < 4; q++) {
        float4 v = efp[q];
        ef[4 * q] = v.x; ef[4 * q + 1] = v.y; ef[4 * q + 2] = v.z; ef[4 * q + 3] = v.w;
    }
    float o0[4] = {0.f, 0.f, 0.f, 0.f};
    float o1[4] = {0.f, 0.f, 0.f, 0.f};
    float o2 = 0.f;
#pragma unroll
    for (int f = 0; f < EF_DIM; f++) {
        float v = ef[f];
#pragma unroll
        for (int hh = 0; hh < 4; hh++) {
            o0[hh] += v * sM[f * 4 + hh];
            o1[hh] += v * sM[64 + f * 4 + hh];
        }
        o2 += v * sM[128 + f];
    }
    f16x4 a = {(_Float16)o0[0], (_Float16)o0[1], (_Float16)o0[2], (_Float16)o0[3]};
    f16x4 c = {(_Float16)o1[0], (_Float16)o1[1], (_Float16)o1[2], (_Float16)o1[3]};
    ((f16x4*)ep0)[i] = a;
    ((f16x4*)ep1)[i] = c;
    ep2[i] = (_Float16)o2;
}

// ============================ per-layer kernels ============================

// feat = Xh @ W via MFMA 16x16x16 f16, B-frags straight from L1-resident Wht[n][k].
// Fused epilogue computes el/er from accumulators (coefficient for col c is al[c];
// head(col) = nt>>1 for D=32, 0 for D=128 — compile-time under unroll).
// A: row=lane&15, k=(lane>>4)*4+j ; D: col=lane&15, row=(lane>>4)*4+r (harness-verified).
template <int H>
__global__ __launch_bounds__(256) void k_feat(const _Float16* __restrict__ Xh,
                                              const _Float16* __restrict__ Wht,
                                              const float* __restrict__ al,
                                              const float* __restrict__ ar,
                                              _Float16* __restrict__ Fh,
                                              float* __restrict__ el,
                                              float* __restrict__ er) {
    const int t = threadIdx.x;
    const int lane = t & 63;
    const int wv = t >> 6;
    const int l15 = lane & 15;
    const int kg = lane >> 4;
    const int nbase = blockIdx.x * 64;
    const int arow = nbase + wv * 16 + l15;
    const int rclamp = (arow < NN) ? arow : NN - 1;
    const int ksub = kg * 4;
    f16x4 a[8];
#pragma unroll
    for (int kb = 0; kb < 8; kb++)
        a[kb] = *(const f16x4*)(Xh + (size_t)rclamp * 128 + kb * 16 + ksub);

    const int r0 = nbase + wv * 16 + kg * 4;  // acc rows r0..r0+3
    float slp[4][H], srp[4][H];
#pragma unroll
    for (int r = 0; r < 4; r++)
#pragma unroll
        for (int hh = 0; hh < H; hh++) { slp[r][hh] = 0.f; srp[r][hh] = 0.f; }

#pragma unroll
    for (int nt = 0; nt < 8; nt++) {
        f32x4 acc = {0.f, 0.f, 0.f, 0.f};
        const int nc = nt * 16 + l15;
        const _Float16* wp = Wht + (size_t)nc * 128;
#pragma unroll
        for (int kb = 0; kb < 8; kb++) {
            f16x4 bf = *(const f16x4*)(wp + kb * 16 + ksub);
            acc = __builtin_amdgcn_mfma_f32_16x16x16f16(a[kb], bf, acc, 0, 0, 0);
        }
        const float alv = al[nc], arv = ar[nc];
        constexpr int HSEL = 0;  // placeholder for H==1
        const int hsel = (H == 4) ? (nt >> 1) : HSEL;
#pragma unroll
        for (int r = 0; r < 4; r++) {
            int ro = r0 + r;
            if (ro < NN) Fh[(size_t)ro * 128 + nc] = (_Float16)acc[r];
            slp[r][hsel] += acc[r] * alv;
            srp[r][hsel] += acc[r] * arv;
        }
    }

    // reduce partials across the 16 lanes of each kg-group
#pragma unroll
    for (int m = 1; m < 16; m <<= 1)
#pragma unroll
        for (int r = 0; r < 4; r++)
#pragma unroll
            for (int hh = 0; hh < H; hh++) {
                slp[r][hh] += __shfl_xor(slp[r][hh], m);
                srp[r][hh] += __shfl_xor(srp[r][hh], m);
            }

    if (H == 4) {
        int r = l15 >> 2, hh2 = l15 & 3;
        float sv = 0.f, ev = 0.f;
#pragma unroll
        for (int rr = 0; rr < 4; rr++)
#pragma unroll
            for (int hc = 0; hc < H; hc++)
                if (rr == r && hc == hh2) { sv = slp[rr][hc]; ev = srp[rr][hc]; }
        int ro = r0 + r;
        if (ro < NN) { el[ro * 4 + hh2] = sv; er[ro * 4 + hh2] = ev; }
    } else {
        if (l15 < 4) {
            float sv = 0.f, ev = 0.f;
#pragma unroll
            for (int rr = 0; rr < 4; rr++)
                if (rr == l15) { sv = slp[rr][0]; ev = srp[rr][0]; }
            int ro = r0 + l15;
            if (ro < NN) { el[ro] = sv; er[ro] = ev; }
        }
    }
}

// fused per-dst-node: score + softmax + aggregation. One WAVE per node.
template <int H, int D, int OUT16>
__global__ __launch_bounds__(256) void k_node(const int* __restrict__ row_ptr,
                                              const int2* __restrict__ epr,
                                              const _Float16* __restrict__ ep,
                                              const float* __restrict__ el,
                                              const float* __restrict__ er,
                                              const __half2* __restrict__ Fh,
                                              const float* __restrict__ bias,
                                              float* __restrict__ Rf,
                                              _Float16* __restrict__ Rh,
                                              int act) {
    __shared__ float wlds[4][256];
    const int wave = threadIdx.x >> 6;
    const int lane = threadIdx.x & 63;
    const int n = blockIdx.x * 4 + wave;  // grid exactly NN/4
    const int start = row_ptr[n];
    const int end = row_ptr[n + 1];
    const int len = end - start;
    const int slots = len * H;
    const int c = 2 * lane;
    const int hcol = c / D;
    float2 b2 = make_float2(bias[c], bias[c + 1]);
    float2 a = make_float2(0.f, 0.f);

    if (len > 0) {
        constexpr int hsh = (H == 4) ? 2 : 0;
        const int hh = lane & (H - 1);
        const float er_j = er[n * H + hh];
        const _Float16* epb = ep + (size_t)start * H;
        float pmax = -3.0e38f, psum = 0.f;

        if (slots <= 256) {
            float* wp = wlds[wave];
            for (int jj = lane; jj < slots; jj += 64) {
                int i = start + (jj >> hsh);
                float x = el[epr[i].y * H + hh] + er_j + (float)epb[jj];
                x = (x > 0.f) ? x : 0.2f * x;
                wp[jj] = x;
                pmax = fmaxf(pmax, x);
            }
            for (int m = H; m < 64; m <<= 1) pmax = fmaxf(pmax, __shfl_xor(pmax, m));
            for (int jj = lane; jj < slots; jj += 64) {
                float ex = __expf(wp[jj] - pmax);
                wp[jj] = ex;
                psum += ex;
            }
            for (int m = H; m < 64; m <<= 1) psum += __shfl_xor(psum, m);
            const float inv = 1.f / __shfl(psum, hcol);
#pragma unroll 4
            for (int i = start; i < end; i++) {
                float w = wp[(i - start) * H + hcol];
                float2 f2 = __half22float2(Fh[(size_t)epr[i].y * 64 + lane]);
                a.x += f2.x * w;
                a.y += f2.y * w;
            }
            a.x *= inv;
            a.y *= inv;
        } else {  // recompute fallback (unreachable for this graph; kept for correctness)
            for (int jj = lane; jj < slots; jj += 64) {
                int i = start + (jj >> hsh);
                float x = el[epr[i].y * H + hh] + er_j + (float)epb[jj];
                x = (x > 0.f) ? x : 0.2f * x;
                pmax = fmaxf(pmax, x);
            }
            for (int m = H; m < 64; m <<= 1) pmax = fmaxf(pmax, __shfl_xor(pmax, m));
            for (int jj = lane; jj < slots; jj += 64) {
                int i = start + (jj >> hsh);
                float x = el[epr[i].y * H + hh] + er_j + (float)epb[jj];
                x = (x > 0.f) ? x : 0.2f * x;
                psum += __expf(x - pmax);
            }
            for (int m = H; m < 64; m <<= 1) psum += __shfl_xor(psum, m);
            const float inv = 1.f / __shfl(psum, hcol);
            const float pm_c = __shfl(pmax, hcol);
            const float er_c = er[n * H + hcol];
            for (int i = start; i < end; i++) {
                int sn = epr[i].y;
                float x = el[sn * H + hcol] + er_c + (float)epb[(i - start) * H + hcol];
                x = (x > 0.f) ? x : 0.2f * x;
                float w = __expf(x - pm_c);
                float2 f2 = __half22float2(Fh[(size_t)sn * 64 + lane]);
                a.x += f2.x * w;
                a.y += f2.y * w;
            }
            a.x *= inv;
            a.y *= inv;
        }
    }

    float2 v = make_float2(a.x + b2.x, a.y + b2.y);
    if (act) { v.x = fmaxf(v.x, 0.f); v.y = fmaxf(v.y, 0.f); }
    if (OUT16)
        ((__half2*)Rh)[(size_t)n * 64 + lane] = __floats2half2_rn(v.x, v.y);
    else
        ((float2*)Rf)[(size_t)n * 64 + lane] = v;
}

// ============================ driver ============================

extern "C" void kernel_launch(void* const* d_in, const int* in_sizes, int n_in,
                              void* d_out, int out_size, void* d_ws, size_t ws_size,
                              hipStream_t stream) {
    const float* h   = (const float*)d_in[0];
    const float* eft = (const float*)d_in[1];
    const int* src   = (const int*)d_in[2];
    const int* dst   = (const int*)d_in[3];
    auto P = [&](int i) { return (const float*)d_in[i]; };

    float* ws = (float*)d_ws;
    _Float16* Fh   = (_Float16*)ws;                     // NN*128 halves
    _Float16* Xh   = Fh + (size_t)NN * 128;             // NN*128 halves
    _Float16* Wht  = Xh + (size_t)NN * 128;             // 3*128*128 halves
    _Float16* ep0  = Wht + 3 * 16384;                   // NE*4 halves
    _Float16* ep1  = ep0 + (size_t)NE * 4;              // NE*4 halves
    _Float16* ep2  = ep1 + (size_t)NE * 4;              // NE halves
    float* el      = (float*)(ep2 + NE);                // NN*4
    float* er      = el + (size_t)NN * 4;               // NN*4
    float* M       = er + (size_t)NN * 4;               // 192
    int2* epr      = (int2*)(M + 192);                  // NE int2
    int* row_ptr   = (int*)(epr + NE);                  // NN+1
    int* cursor    = row_ptr + (NN + 1);                // NN
    int* deg       = cursor + NN;                       // NN
    int* part      = deg + NN;                          // NPARTS
    float* out     = (float*)d_out;

    // ---- one-time prep + sorted CSR + edge projections ----
    hipLaunchKernelGGL(k_prep, dim3(391 + (NN * 32 + 255) / 256), dim3(256), 0, stream,
                       h, P(5), P(8), P(11), P(14), P(17), P(20),
                       P(4), P(10), P(16), deg, M, Wht, Xh);
    hipLaunchKernelGGL(k_hist, dim3((NE + 255) / 256), dim3(256), 0, stream, dst, deg);
    hipLaunchKernelGGL(k_part, dim3(NPARTS), dim3(SCAN_B), 0, stream, deg, part);
    hipLaunchKernelGGL(k_scanpart, dim3(1), dim3(SCAN_B), 0, stream, part);
    hipLaunchKernelGGL(k_rowptr, dim3(NPARTS), dim3(SCAN_B), 0, stream,
                       deg, part, row_ptr, cursor);
    hipLaunchKernelGGL(k_scatter, dim3((NE + 255) / 256), dim3(256), 0, stream,
                       src, dst, cursor, epr);
    hipLaunchKernelGGL(k_segsort, dim3(NN / 4), dim3(256), 0, stream, row_ptr, epr);
    hipLaunchKernelGGL(k_eproj, dim3((NE + 255) / 256), dim3(256), 0, stream,
                       eft, epr, M, ep0, ep1, ep2);

    const int FG = (NN + 63) / 64;
    // layer 0: Xh -> Xh (fp16, relu)
    hipLaunchKernelGGL((k_feat<4>), dim3(FG), dim3(256), 0, stream,
                       Xh, Wht, P(6), P(7), Fh, el, er);
    hipLaunchKernelGGL((k_node<4, 32, 1>), dim3(NN / 4), dim3(256), 0, stream,
                       row_ptr, epr, ep0, el, er, (const __half2*)Fh, P(9),
                       nullptr, Xh, 1);
    // layer 1: Xh -> Xh (fp16, relu)
    hipLaunchKernelGGL((k_feat<4>), dim3(FG), dim3(256), 0, stream,
                       Xh, Wht + 16384, P(12), P(13), Fh, el, er);
    hipLaunchKernelGGL((k_node<4, 32, 1>), dim3(NN / 4), dim3(256), 0, stream,
                       row_ptr, epr, ep1, el, er, (const __half2*)Fh, P(15),
                       nullptr, Xh, 1);
    // layer 2: Xh -> out (fp32, no act)
    hipLaunchKernelGGL((k_feat<1>), dim3(FG), dim3(256), 0, stream,
                       Xh, Wht + 32768, P(18), P(19), Fh, el, er);
    hipLaunchKernelGGL((k_node<1, 128, 0>), dim3(NN / 4), dim3(256), 0, stream,
                       row_ptr, epr, ep2, el, er, (const __half2*)Fh, P(21),
                       out, nullptr, 0);
}

// Round 8
// 391.183 us; speedup vs baseline: 1.3667x; 1.0510x over previous
//
#include <hip/hip_runtime.h>
#include <hip/hip_fp16.h>
#include <cstdint>

#define NN 50000
#define NE 800000
static constexpr int HD = 128;     // H*D for every layer
static constexpr int EF_DIM = 16;  // edge feature dim
static constexpr int SCAN_B = 256;
static constexpr int NPARTS = (NN + SCAN_B - 1) / SCAN_B;  // 196

typedef _Float16 f16x4 __attribute__((ext_vector_type(4)));
typedef float f32x4 __attribute__((ext_vector_type(4)));

// 32B edge payload (stored in a 64B slot so the scatter write is a full line)
struct RecP {
    int src;
    int e;
    f16x4 p0;       // layer0 ep (4 heads)
    f16x4 p1;       // layer1 ep
    _Float16 p2;    // layer2 ep
    _Float16 pad;
};
union Rec32 { RecP r; float4 v[2]; };

// ============================ prep (merged, once) ============================
// blocks [0,196): zero deg | [196,199): M3 | [199,391): Wht transpose+cvt |
// [391,...): Xh fp32->fp16
__global__ __launch_bounds__(256) void k_prep(const float* __restrict__ h,
        const float* __restrict__ We0, const float* __restrict__ ae0,
        const float* __restrict__ We1, const float* __restrict__ ae1,
        const float* __restrict__ We2, const float* __restrict__ ae2,
        const float* __restrict__ W0, const float* __restrict__ W1,
        const float* __restrict__ W2,
        int* __restrict__ deg, float* __restrict__ M,
        _Float16* __restrict__ Wht, _Float16* __restrict__ Xh) {
    const int b = blockIdx.x, t = threadIdx.x;
    if (b < 196) {
        int i = b * 256 + t;
        if (i < NN) deg[i] = 0;
        return;
    }
    if (b < 199) {
        int l = b - 196;
        const float* We = (l == 0) ? We0 : (l == 1) ? We1 : We2;
        const float* ae = (l == 0) ? ae0 : (l == 1) ? ae1 : ae2;
        int H = (l == 2) ? 1 : 4, D = (l == 2) ? 128 : 32;
        if (t < EF_DIM * H) {
            int f = t / H, hh = t % H;
            float s = 0.f;
            for (int d = 0; d < D; d++) s += We[f * HD + hh * D + d] * ae[hh * D + d];
            M[l * 64 + f * H + hh] = s;
        }
        return;
    }
    if (b < 391) {
        int i = (b - 199) * 256 + t;     // over 3*128*128
        int l = i >> 14, rem = i & 16383;
        int n = rem >> 7, k = rem & 127;
        const float* W = (l == 0) ? W0 : (l == 1) ? W1 : W2;
        Wht[(size_t)l * 16384 + n * 128 + k] = (_Float16)W[k * 128 + n];
        return;
    }
    {
        int i = (b - 391) * 256 + t;     // over NN*32 float4's
        if (i < NN * 32) {
            float4 v = ((const float4*)h)[i];
            f16x4 o = {(_Float16)v.x, (_Float16)v.y, (_Float16)v.z, (_Float16)v.w};
            ((f16x4*)Xh)[i] = o;
        }
    }
}

// ============================ CSR build (once) ============================

__global__ void k_hist(const int* __restrict__ dst, int* __restrict__ deg) {
    int e = blockIdx.x * blockDim.x + threadIdx.x;
    if (e < NE) atomicAdd(&deg[dst[e]], 1);
}

__global__ __launch_bounds__(SCAN_B) void k_part(const int* __restrict__ deg,
                                                 int* __restrict__ part) {
    __shared__ int s[SCAN_B];
    int t = threadIdx.x;
    int i = blockIdx.x * SCAN_B + t;
    s[t] = (i < NN) ? deg[i] : 0;
    __syncthreads();
    for (int off = SCAN_B / 2; off > 0; off >>= 1) {
        if (t < off) s[t] += s[t + off];
        __syncthreads();
    }
    if (t == 0) part[blockIdx.x] = s[0];
}

__global__ __launch_bounds__(SCAN_B) void k_scanpart(int* __restrict__ part) {
    __shared__ int s[SCAN_B];
    int t = threadIdx.x;
    int v = (t < NPARTS) ? part[t] : 0;
    s[t] = v;
    __syncthreads();
    for (int off = 1; off < SCAN_B; off <<= 1) {
        int u = (t >= off) ? s[t - off] : 0;
        __syncthreads();
        s[t] += u;
        __syncthreads();
    }
    if (t < NPARTS) part[t] = s[t] - v;  // exclusive
}

__global__ __launch_bounds__(SCAN_B) void k_rowptr(const int* __restrict__ deg,
                                                   const int* __restrict__ part,
                                                   int* __restrict__ row_ptr,
                                                   int* __restrict__ cursor) {
    __shared__ int s[SCAN_B];
    int t = threadIdx.x;
    int i = blockIdx.x * SCAN_B + t;
    int v = (i < NN) ? deg[i] : 0;
    s[t] = v;
    __syncthreads();
    for (int off = 1; off < SCAN_B; off <<= 1) {
        int u = (t >= off) ? s[t - off] : 0;
        __syncthreads();
        s[t] += u;
        __syncthreads();
    }
    int excl = s[t] - v + part[blockIdx.x];
    if (i < NN) { row_ptr[i] = excl; cursor[i] = excl; }
    if (i == NN) row_ptr[NN] = NE;
}

// scatter + edge projection fused: coalesced EF read in original edge order,
// one FULL-LINE (64B) random write per edge -> no partial-line writebacks.
__global__ __launch_bounds__(256) void k_scat64(const int* __restrict__ src,
                                                const int* __restrict__ dst,
                                                const float* __restrict__ EFt,
                                                const float* __restrict__ M,
                                                int* __restrict__ cursor,
                                                float4* __restrict__ rec) {
    __shared__ float sM[192];
    int t = threadIdx.x;
    if (t < 192) sM[t] = M[t];
    __syncthreads();
    int e = blockIdx.x * 256 + t;
    if (e >= NE) return;
    float ef[EF_DIM];
    const float4* efp = (const float4*)(EFt + (size_t)e * EF_DIM);
#pragma unroll
    for (int q = 0; q < 4; q++) {
        float4 v = efp[q];
        ef[4 * q] = v.x; ef[4 * q + 1] = v.y; ef[4 * q + 2] = v.z; ef[4 * q + 3] = v.w;
    }
    float o0[4] = {0.f, 0.f, 0.f, 0.f};
    float o1[4] = {0.f, 0.f, 0.f, 0.f};
    float o2 = 0.f;
#pragma unroll
    for (int f = 0; f < EF_DIM; f++) {
        float v = ef[f];
#pragma unroll
        for (int hh = 0; hh < 4; hh++) {
            o0[hh] += v * sM[f * 4 + hh];
            o1[hh] += v * sM[64 + f * 4 + hh];
        }
        o2 += v * sM[128 + f];
    }
    Rec32 u;
    u.r.src = src[e];
    u.r.e = e;
    u.r.p0 = f16x4{(_Float16)o0[0], (_Float16)o0[1], (_Float16)o0[2], (_Float16)o0[3]};
    u.r.p1 = f16x4{(_Float16)o1[0], (_Float16)o1[1], (_Float16)o1[2], (_Float16)o1[3]};
    u.r.p2 = (_Float16)o2;
    u.r.pad = (_Float16)0.f;
    int d = dst[e];
    int pos = atomicAdd(&cursor[d], 1);
    float4* p = rec + (size_t)pos * 4;
    p[0] = u.v[0];
    p[1] = u.v[1];
    p[2] = make_float4(0.f, 0.f, 0.f, 0.f);   // fill the line: full 64B dirty
    p[3] = make_float4(0.f, 0.f, 0.f, 0.f);
}

// per-segment rank sort by (src, e) -> compact sequential SoA outputs.
__global__ __launch_bounds__(256) void k_segsort2(const int* __restrict__ row_ptr,
                                                  const float4* __restrict__ rec,
                                                  int* __restrict__ ssrc,
                                                  f16x4* __restrict__ ep0,
                                                  f16x4* __restrict__ ep1,
                                                  _Float16* __restrict__ ep2) {
    __shared__ Rec32 seg[4][128];  // 16 KB
    const int wave = threadIdx.x >> 6;
    const int lane = threadIdx.x & 63;
    const int n = blockIdx.x * 4 + wave;  // grid exactly NN/4
    const int start = row_ptr[n];
    const int len = row_ptr[n + 1] - start;
    const bool small = (len > 0 && len <= 128);
    if (small)
        for (int s = lane; s < len; s += 64) {
            seg[wave][s].v[0] = rec[(size_t)(start + s) * 4];
            seg[wave][s].v[1] = rec[(size_t)(start + s) * 4 + 1];
        }
    __syncthreads();
    if (small) {
        for (int s = lane; s < len; s += 64) {
            RecP me = seg[wave][s].r;
            int rank = 0;
            for (int j = 0; j < len; j++) {
                const RecP& o = seg[wave][j].r;
                rank += (o.src < me.src) || (o.src == me.src && o.e < me.e);
            }
            int w = start + rank;
            ssrc[w] = me.src;
            ep0[w] = me.p0;
            ep1[w] = me.p1;
            ep2[w] = me.p2;
        }
    } else if (len > 128) {  // fallback: arrival order (valid; unreachable for this graph)
        for (int s = lane; s < len; s += 64) {
            Rec32 u;
            u.v[0] = rec[(size_t)(start + s) * 4];
            u.v[1] = rec[(size_t)(start + s) * 4 + 1];
            int w = start + s;
            ssrc[w] = u.r.src;
            ep0[w] = u.r.p0;
            ep1[w] = u.r.p1;
            ep2[w] = u.r.p2;
        }
    }
}

// ============================ per-layer kernels ============================

// feat = Xh @ W via MFMA 16x16x16 f16, B-frags from L1-resident Wht[n][k].
// Fused epilogue computes el/er from accumulators.
template <int H>
__global__ __launch_bounds__(256) void k_feat(const _Float16* __restrict__ Xh,
                                              const _Float16* __restrict__ Wht,
                                              const float* __restrict__ al,
                                              const float* __restrict__ ar,
                                              _Float16* __restrict__ Fh,
                                              float* __restrict__ el,
                                              float* __restrict__ er) {
    const int t = threadIdx.x;
    const int lane = t & 63;
    const int wv = t >> 6;
    const int l15 = lane & 15;
    const int kg = lane >> 4;
    const int nbase = blockIdx.x * 64;
    const int arow = nbase + wv * 16 + l15;
    const int rclamp = (arow < NN) ? arow : NN - 1;
    const int ksub = kg * 4;
    f16x4 a[8];
#pragma unroll
    for (int kb = 0; kb < 8; kb++)
        a[kb] = *(const f16x4*)(Xh + (size_t)rclamp * 128 + kb * 16 + ksub);

    const int r0 = nbase + wv * 16 + kg * 4;  // acc rows r0..r0+3
    float slp[4][H], srp[4][H];
#pragma unroll
    for (int r = 0; r < 4; r++)
#pragma unroll
        for (int hh = 0; hh < H; hh++) { slp[r][hh] = 0.f; srp[r][hh] = 0.f; }

#pragma unroll
    for (int nt = 0; nt < 8; nt++) {
        f32x4 acc = {0.f, 0.f, 0.f, 0.f};
        const int nc = nt * 16 + l15;
        const _Float16* wp = Wht + (size_t)nc * 128;
#pragma unroll
        for (int kb = 0; kb < 8; kb++) {
            f16x4 bf = *(const f16x4*)(wp + kb * 16 + ksub);
            acc = __builtin_amdgcn_mfma_f32_16x16x16f16(a[kb], bf, acc, 0, 0, 0);
        }
        const float alv = al[nc], arv = ar[nc];
        constexpr int HSEL = 0;
        const int hsel = (H == 4) ? (nt >> 1) : HSEL;
#pragma unroll
        for (int r = 0; r < 4; r++) {
            int ro = r0 + r;
            if (ro < NN) Fh[(size_t)ro * 128 + nc] = (_Float16)acc[r];
            slp[r][hsel] += acc[r] * alv;
            srp[r][hsel] += acc[r] * arv;
        }
    }

#pragma unroll
    for (int m = 1; m < 16; m <<= 1)
#pragma unroll
        for (int r = 0; r < 4; r++)
#pragma unroll
            for (int hh = 0; hh < H; hh++) {
                slp[r][hh] += __shfl_xor(slp[r][hh], m);
                srp[r][hh] += __shfl_xor(srp[r][hh], m);
            }

    if (H == 4) {
        int r = l15 >> 2, hh2 = l15 & 3;
        float sv = 0.f, ev = 0.f;
#pragma unroll
        for (int rr = 0; rr < 4; rr++)
#pragma unroll
            for (int hc = 0; hc < H; hc++)
                if (rr == r && hc == hh2) { sv = slp[rr][hc]; ev = srp[rr][hc]; }
        int ro = r0 + r;
        if (ro < NN) { el[ro * 4 + hh2] = sv; er[ro * 4 + hh2] = ev; }
    } else {
        if (l15 < 4) {
            float sv = 0.f, ev = 0.f;
#pragma unroll
            for (int rr = 0; rr < 4; rr++)
                if (rr == l15) { sv = slp[rr][0]; ev = srp[rr][0]; }
            int ro = r0 + l15;
            if (ro < NN) { el[ro] = sv; er[ro] = ev; }
        }
    }
}

// fused per-dst-node: score + softmax + aggregation. One WAVE per node.
template <int H, int D, int OUT16>
__global__ __launch_bounds__(256) void k_node(const int* __restrict__ row_ptr,
                                              const int* __restrict__ ssrc,
                                              const _Float16* __restrict__ ep,
                                              const float* __restrict__ el,
                                              const float* __restrict__ er,
                                              const __half2* __restrict__ Fh,
                                              const float* __restrict__ bias,
                                              float* __restrict__ Rf,
                                              _Float16* __restrict__ Rh,
                                              int act) {
    __shared__ float wlds[4][256];
    const int wave = threadIdx.x >> 6;
    const int lane = threadIdx.x & 63;
    const int n = blockIdx.x * 4 + wave;  // grid exactly NN/4
    const int start = row_ptr[n];
    const int end = row_ptr[n + 1];
    const int len = end - start;
    const int slots = len * H;
    const int c = 2 * lane;
    const int hcol = c / D;
    float2 b2 = make_float2(bias[c], bias[c + 1]);
    float2 a = make_float2(0.f, 0.f);

    if (len > 0) {
        constexpr int hsh = (H == 4) ? 2 : 0;
        const int hh = lane & (H - 1);
        const float er_j = er[n * H + hh];
        const _Float16* epb = ep + (size_t)start * H;
        float pmax = -3.0e38f, psum = 0.f;

        if (slots <= 256) {
            float* wp = wlds[wave];
            for (int jj = lane; jj < slots; jj += 64) {
                int i = start + (jj >> hsh);
                float x = el[ssrc[i] * H + hh] + er_j + (float)epb[jj];
                x = (x > 0.f) ? x : 0.2f * x;
                wp[jj] = x;
                pmax = fmaxf(pmax, x);
            }
            for (int m = H; m < 64; m <<= 1) pmax = fmaxf(pmax, __shfl_xor(pmax, m));
            for (int jj = lane; jj < slots; jj += 64) {
                float ex = __expf(wp[jj] - pmax);
                wp[jj] = ex;
                psum += ex;
            }
            for (int m = H; m < 64; m <<= 1) psum += __shfl_xor(psum, m);
            const float inv = 1.f / __shfl(psum, hcol);
#pragma unroll 4
            for (int i = start; i < end; i++) {
                float w = wp[(i - start) * H + hcol];
                float2 f2 = __half22float2(Fh[(size_t)ssrc[i] * 64 + lane]);
                a.x += f2.x * w;
                a.y += f2.y * w;
            }
            a.x *= inv;
            a.y *= inv;
        } else {  // recompute fallback (unreachable for this graph; kept for correctness)
            for (int jj = lane; jj < slots; jj += 64) {
                int i = start + (jj >> hsh);
                float x = el[ssrc[i] * H + hh] + er_j + (float)epb[jj];
                x = (x > 0.f) ? x : 0.2f * x;
                pmax = fmaxf(pmax, x);
            }
            for (int m = H; m < 64; m <<= 1) pmax = fmaxf(pmax, __shfl_xor(pmax, m));
            for (int jj = lane; jj < slots; jj += 64) {
                int i = start + (jj >> hsh);
                float x = el[ssrc[i] * H + hh] + er_j + (float)epb[jj];
                x = (x > 0.f) ? x : 0.2f * x;
                psum += __expf(x - pmax);
            }
            for (int m = H; m < 64; m <<= 1) psum += __shfl_xor(psum, m);
            const float inv = 1.f / __shfl(psum, hcol);
            const float pm_c = __shfl(pmax, hcol);
            const float er_c = er[n * H + hcol];
            for (int i = start; i < end; i++) {
                int sn = ssrc[i];
                float x = el[sn * H + hcol] + er_c + (float)epb[(i - start) * H + hcol];
                x = (x > 0.f) ? x : 0.2f * x;
                float w = __expf(x - pm_c);
                float2 f2 = __half22float2(Fh[(size_t)sn * 64 + lane]);
                a.x += f2.x * w;
                a.y += f2.y * w;
            }
            a.x *= inv;
            a.y *= inv;
        }
    }

    float2 v = make_float2(a.x + b2.x, a.y + b2.y);
    if (act) { v.x = fmaxf(v.x, 0.f); v.y = fmaxf(v.y, 0.f); }
    if (OUT16)
        ((__half2*)Rh)[(size_t)n * 64 + lane] = __floats2half2_rn(v.x, v.y);
    else
        ((float2*)Rf)[(size_t)n * 64 + lane] = v;
}

// ============================ driver ============================

extern "C" void kernel_launch(void* const* d_in, const int* in_sizes, int n_in,
                              void* d_out, int out_size, void* d_ws, size_t ws_size,
                              hipStream_t stream) {
    const float* h   = (const float*)d_in[0];
    const float* eft = (const float*)d_in[1];
    const int* src   = (const int*)d_in[2];
    const int* dst   = (const int*)d_in[3];
    auto P = [&](int i) { return (const float*)d_in[i]; };

    float* ws = (float*)d_ws;
    // rec occupies [0, 12.8M floats); transient (dead after k_segsort2).
    float4* rec    = (float4*)ws;                       // NE * 64B
    _Float16* Fh   = (_Float16*)ws;                     // overlay: NN*128 halves (3.2M f)
    float* el      = ws + 3200000;                      // overlay: NN*4
    float* er      = ws + 3400000;                      // overlay: NN*4
    _Float16* Xh   = (_Float16*)(ws + 12800000);        // NN*128 halves (3.2M f)
    _Float16* Wht  = (_Float16*)(ws + 16000000);        // 3*128*128 halves
    _Float16* ep0s = Wht + 3 * 16384;                   // NE*4 halves (1.6M f)
    _Float16* ep1s = ep0s + (size_t)NE * 4;             // NE*4 halves
    _Float16* ep2s = ep1s + (size_t)NE * 4;             // NE halves (0.4M f)
    int* ssrc      = (int*)(ep2s + NE);                 // NE ints
    float* M       = (float*)(ssrc + NE);               // 192
    int* row_ptr   = (int*)(M + 192);                   // NN+1
    int* cursor    = row_ptr + (NN + 1);                // NN
    int* deg       = cursor + NN;                       // NN
    int* part      = deg + NN;                          // NPARTS
    float* out     = (float*)d_out;

    // ---- one-time prep + sorted CSR (payload-carrying) ----
    hipLaunchKernelGGL(k_prep, dim3(391 + (NN * 32 + 255) / 256), dim3(256), 0, stream,
                       h, P(5), P(8), P(11), P(14), P(17), P(20),
                       P(4), P(10), P(16), deg, M, Wht, Xh);
    hipLaunchKernelGGL(k_hist, dim3((NE + 255) / 256), dim3(256), 0, stream, dst, deg);
    hipLaunchKernelGGL(k_part, dim3(NPARTS), dim3(SCAN_B), 0, stream, deg, part);
    hipLaunchKernelGGL(k_scanpart, dim3(1), dim3(SCAN_B), 0, stream, part);
    hipLaunchKernelGGL(k_rowptr, dim3(NPARTS), dim3(SCAN_B), 0, stream,
                       deg, part, row_ptr, cursor);
    hipLaunchKernelGGL(k_scat64, dim3((NE + 255) / 256), dim3(256), 0, stream,
                       src, dst, eft, M, cursor, rec);
    hipLaunchKernelGGL(k_segsort2, dim3(NN / 4), dim3(256), 0, stream,
                       row_ptr, rec, ssrc, (f16x4*)ep0s, (f16x4*)ep1s, ep2s);

    const int FG = (NN + 63) / 64;
    // layer 0: Xh -> Xh (fp16, relu)
    hipLaunchKernelGGL((k_feat<4>), dim3(FG), dim3(256), 0, stream,
                       Xh, Wht, P(6), P(7), Fh, el, er);
    hipLaunchKernelGGL((k_node<4, 32, 1>), dim3(NN / 4), dim3(256), 0, stream,
                       row_ptr, ssrc, ep0s, el, er, (const __half2*)Fh, P(9),
                       nullptr, Xh, 1);
    // layer 1: Xh -> Xh (fp16, relu)
    hipLaunchKernelGGL((k_feat<4>), dim3(FG), dim3(256), 0, stream,
                       Xh, Wht + 16384, P(12), P(13), Fh, el, er);
    hipLaunchKernelGGL((k_node<4, 32, 1>), dim3(NN / 4), dim3(256), 0, stream,
                       row_ptr, ssrc, ep1s, el, er, (const __half2*)Fh, P(15),
                       nullptr, Xh, 1);
    // layer 2: Xh -> out (fp32, no act)
    hipLaunchKernelGGL((k_feat<1>), dim3(FG), dim3(256), 0, stream,
                       Xh, Wht + 32768, P(18), P(19), Fh, el, er);
    hipLaunchKernelGGL((k_node<1, 128, 0>), dim3(NN / 4), dim3(256), 0, stream,
                       row_ptr, ssrc, ep2s, el, er, (const __half2*)Fh, P(21),
                       out, nullptr, 0);
}